// Round 1
// baseline (5885.231 us; speedup 1.0000x reference)
//
#include <hip/hip_runtime.h>

#define N_NODES 100000
#define N_EDGES 1600000
#define DIM 128

// ---------------------------------------------------------------------------
// Pass 1: edge scatter. 32 threads per edge, each handles 4 channels (float4
// gather from x[src], 4 scalar float atomicAdds into s[dst]). cnt computed
// only on the first layer (dst identical across layers).
// ---------------------------------------------------------------------------
__global__ __launch_bounds__(256) void scatter_k(
    const float* __restrict__ x, const int* __restrict__ ei,
    float* __restrict__ s, float* __restrict__ cnt, int do_cnt)
{
    int tid = blockIdx.x * 256 + threadIdx.x;
    int e = tid >> 5;
    if (e >= N_EDGES) return;
    int lane = tid & 31;
    int src = ei[e];
    int dst = ei[N_EDGES + e];
    float4 v = *(const float4*)(x + src * DIM + lane * 4);
    float* p = s + dst * DIM + lane * 4;
    atomicAdd(p + 0, v.x);
    atomicAdd(p + 1, v.y);
    atomicAdd(p + 2, v.z);
    atomicAdd(p + 3, v.w);
    if (do_cnt && lane == 0) atomicAdd(cnt + dst, 1.0f);
}

// ---------------------------------------------------------------------------
// Pass 2: h1 = (x + s/max(cnt,1)) @ W1 + b1, with fused BN-stat accumulation
// (per-column sum and sum-of-squares). 64 rows/block, 16x16 threads, each
// thread computes a 4x8 accumulator tile. A-tile staged in LDS (pad 132 so
// float4 stores stay 16B-aligned; bank aliasing is only 2-way = free).
// W (64 KB) streamed from L1/L2 directly — fully cache-resident.
// ---------------------------------------------------------------------------
__global__ __launch_bounds__(256) void gemm_agg_k(
    const float* __restrict__ xin, const float* __restrict__ s, const float* __restrict__ cnt,
    const float* __restrict__ W, const float* __restrict__ bias,
    float* __restrict__ h1, float* __restrict__ colsum, float* __restrict__ colsq)
{
    __shared__ float lds[64 * 132];
    const int t = threadIdx.x;
    const int row0 = blockIdx.x * 64;

    // stage A-tile: a[r][c] = x + s*inv_cnt
    for (int i = t; i < 64 * 32; i += 256) {
        int r = i >> 5;
        int c = (i & 31) << 2;
        int gr = row0 + r;
        float4 v = make_float4(0.f, 0.f, 0.f, 0.f);
        if (gr < N_NODES) {
            float4 xv = *(const float4*)(xin + gr * DIM + c);
            float4 sv = *(const float4*)(s + gr * DIM + c);
            float ic = 1.0f / fmaxf(cnt[gr], 1.0f);
            v.x = xv.x + sv.x * ic;
            v.y = xv.y + sv.y * ic;
            v.z = xv.z + sv.z * ic;
            v.w = xv.w + sv.w * ic;
        }
        *(float4*)(lds + r * 132 + c) = v;
    }
    __syncthreads();

    const int tx = t & 15, ty = t >> 4;
    const int j0 = tx * 8;
    float acc[4][8];
    #pragma unroll
    for (int r = 0; r < 4; ++r)
        #pragma unroll
        for (int c = 0; c < 8; ++c) acc[r][c] = 0.f;

    #pragma unroll 4
    for (int k = 0; k < DIM; ++k) {
        float4 w0 = *(const float4*)(W + k * DIM + j0);
        float4 w1 = *(const float4*)(W + k * DIM + j0 + 4);
        float wv[8] = {w0.x, w0.y, w0.z, w0.w, w1.x, w1.y, w1.z, w1.w};
        #pragma unroll
        for (int r = 0; r < 4; ++r) {
            float a = lds[(ty * 4 + r) * 132 + k];
            #pragma unroll
            for (int c = 0; c < 8; ++c) acc[r][c] = fmaf(a, wv[c], acc[r][c]);
        }
    }

    // epilogue: +bias, store h1, per-thread BN partials over valid rows
    float4 bv0 = *(const float4*)(bias + j0);
    float4 bv1 = *(const float4*)(bias + j0 + 4);
    float bb[8] = {bv0.x, bv0.y, bv0.z, bv0.w, bv1.x, bv1.y, bv1.z, bv1.w};
    float psum[8], psq[8];
    #pragma unroll
    for (int c = 0; c < 8; ++c) { psum[c] = 0.f; psq[c] = 0.f; }
    #pragma unroll
    for (int r = 0; r < 4; ++r) {
        int gr = row0 + ty * 4 + r;
        if (gr < N_NODES) {
            float vals[8];
            #pragma unroll
            for (int c = 0; c < 8; ++c) {
                float v = acc[r][c] + bb[c];
                vals[c] = v;
                psum[c] += v;
                psq[c] += v * v;
            }
            *(float4*)(h1 + gr * DIM + j0)     = make_float4(vals[0], vals[1], vals[2], vals[3]);
            *(float4*)(h1 + gr * DIM + j0 + 4) = make_float4(vals[4], vals[5], vals[6], vals[7]);
        }
    }

    // block reduce BN partials across the 16 ty groups (reuse A-tile LDS)
    __syncthreads();
    #pragma unroll
    for (int c = 0; c < 8; ++c) {
        lds[ty * 128 + j0 + c]        = psum[c];
        lds[2048 + ty * 128 + j0 + c] = psq[c];
    }
    __syncthreads();
    if (t < 128) {
        float ss = 0.f, sq = 0.f;
        #pragma unroll
        for (int u = 0; u < 16; ++u) {
            ss += lds[u * 128 + t];
            sq += lds[2048 + u * 128 + t];
        }
        atomicAdd(colsum + t, ss);
        atomicAdd(colsq + t, sq);
    }
}

// ---------------------------------------------------------------------------
// Pass 3: resolve BN stats into per-channel scale/shift (1 block, 128 thr).
// ---------------------------------------------------------------------------
__global__ void bnstats_k(const float* __restrict__ colsum, const float* __restrict__ colsq,
                          const float* __restrict__ gamma, const float* __restrict__ beta,
                          float* __restrict__ scale, float* __restrict__ shift)
{
    int j = threadIdx.x;
    const float inv_n = 1.0f / (float)N_NODES;
    float mu = colsum[j] * inv_n;
    float var = colsq[j] * inv_n - mu * mu;   // biased variance (torch BN)
    float sc = gamma[j] * rsqrtf(var + 1e-5f);
    scale[j] = sc;
    shift[j] = beta[j] - mu * sc;
}

// ---------------------------------------------------------------------------
// Pass 4: out = relu(h1*scale+shift) @ W2 + b2  (optional output relu = the
// inter-layer relu). Same tiling as gemm_agg_k, no stats.
// ---------------------------------------------------------------------------
__global__ __launch_bounds__(256) void gemm_bn_k(
    const float* __restrict__ h1, const float* __restrict__ scale, const float* __restrict__ shift,
    const float* __restrict__ W, const float* __restrict__ bias,
    float* __restrict__ out, int relu_out)
{
    __shared__ float lds[64 * 132];
    const int t = threadIdx.x;
    const int row0 = blockIdx.x * 64;

    for (int i = t; i < 64 * 32; i += 256) {
        int r = i >> 5;
        int c = (i & 31) << 2;
        int gr = row0 + r;
        float4 v = make_float4(0.f, 0.f, 0.f, 0.f);
        if (gr < N_NODES) {
            float4 hv = *(const float4*)(h1 + gr * DIM + c);
            float4 sc = *(const float4*)(scale + c);
            float4 sh = *(const float4*)(shift + c);
            v.x = fmaxf(hv.x * sc.x + sh.x, 0.f);
            v.y = fmaxf(hv.y * sc.y + sh.y, 0.f);
            v.z = fmaxf(hv.z * sc.z + sh.z, 0.f);
            v.w = fmaxf(hv.w * sc.w + sh.w, 0.f);
        }
        *(float4*)(lds + r * 132 + c) = v;
    }
    __syncthreads();

    const int tx = t & 15, ty = t >> 4;
    const int j0 = tx * 8;
    float acc[4][8];
    #pragma unroll
    for (int r = 0; r < 4; ++r)
        #pragma unroll
        for (int c = 0; c < 8; ++c) acc[r][c] = 0.f;

    #pragma unroll 4
    for (int k = 0; k < DIM; ++k) {
        float4 w0 = *(const float4*)(W + k * DIM + j0);
        float4 w1 = *(const float4*)(W + k * DIM + j0 + 4);
        float wv[8] = {w0.x, w0.y, w0.z, w0.w, w1.x, w1.y, w1.z, w1.w};
        #pragma unroll
        for (int r = 0; r < 4; ++r) {
            float a = lds[(ty * 4 + r) * 132 + k];
            #pragma unroll
            for (int c = 0; c < 8; ++c) acc[r][c] = fmaf(a, wv[c], acc[r][c]);
        }
    }

    float4 bv0 = *(const float4*)(bias + j0);
    float4 bv1 = *(const float4*)(bias + j0 + 4);
    float bb[8] = {bv0.x, bv0.y, bv0.z, bv0.w, bv1.x, bv1.y, bv1.z, bv1.w};
    #pragma unroll
    for (int r = 0; r < 4; ++r) {
        int gr = row0 + ty * 4 + r;
        if (gr < N_NODES) {
            float vals[8];
            #pragma unroll
            for (int c = 0; c < 8; ++c) {
                float v = acc[r][c] + bb[c];
                if (relu_out) v = fmaxf(v, 0.f);
                vals[c] = v;
            }
            *(float4*)(out + gr * DIM + j0)     = make_float4(vals[0], vals[1], vals[2], vals[3]);
            *(float4*)(out + gr * DIM + j0 + 4) = make_float4(vals[4], vals[5], vals[6], vals[7]);
        }
    }
}

// ---------------------------------------------------------------------------
// Workspace layout (floats):
//   s      @ 0          : 12,800,000   (scatter accumulator)
//   h1     @ 12,800,000 : 12,800,000   (post-GEMM1 activations)
//   cnt    @ 25,600,000 : 100,000      (in-degree, computed once)
//   colsum @ 25,700,000 : 128
//   colsq  @ +128, scale @ +256, shift @ +384
// Total ~103 MB. d_out doubles as the inter-layer activation buffer (safe:
// the final pass reads only h1/scale/shift before overwriting it).
// ---------------------------------------------------------------------------
extern "C" void kernel_launch(void* const* d_in, const int* in_sizes, int n_in,
                              void* d_out, int out_size, void* d_ws, size_t ws_size,
                              hipStream_t stream)
{
    const float* x    = (const float*)d_in[0];
    const int*   ei   = (const int*)d_in[1];
    const float* W1_0 = (const float*)d_in[2];
    const float* b1_0 = (const float*)d_in[3];
    const float* g_0  = (const float*)d_in[4];
    const float* be_0 = (const float*)d_in[5];
    const float* W2_0 = (const float*)d_in[6];
    const float* b2_0 = (const float*)d_in[7];
    const float* W1_1 = (const float*)d_in[8];
    const float* b1_1 = (const float*)d_in[9];
    const float* g_1  = (const float*)d_in[10];
    const float* be_1 = (const float*)d_in[11];
    const float* W2_1 = (const float*)d_in[12];
    const float* b2_1 = (const float*)d_in[13];
    float* out = (float*)d_out;
    float* ws  = (float*)d_ws;

    float* s      = ws;
    float* h1     = ws + 12800000;
    float* cnt    = ws + 25600000;
    float* colsum = ws + 25700000;
    float* colsq  = colsum + 128;
    float* scale  = colsum + 256;
    float* shift  = colsum + 384;

    dim3 blk(256);
    int scatter_blocks = (N_EDGES * 32) / 256;         // 200,000
    int gemm_blocks    = (N_NODES + 63) / 64;          // 1,563

    // ---- layer 0 ----
    hipMemsetAsync(s, 0, 12800000 * sizeof(float), stream);
    hipMemsetAsync(cnt, 0, 100000 * sizeof(float), stream);
    hipMemsetAsync(colsum, 0, 256 * sizeof(float), stream);
    scatter_k<<<scatter_blocks, blk, 0, stream>>>(x, ei, s, cnt, 1);
    gemm_agg_k<<<gemm_blocks, blk, 0, stream>>>(x, s, cnt, W1_0, b1_0, h1, colsum, colsq);
    bnstats_k<<<1, 128, 0, stream>>>(colsum, colsq, g_0, be_0, scale, shift);
    gemm_bn_k<<<gemm_blocks, blk, 0, stream>>>(h1, scale, shift, W2_0, b2_0, out, 1);

    // ---- layer 1 ----
    hipMemsetAsync(s, 0, 12800000 * sizeof(float), stream);
    hipMemsetAsync(colsum, 0, 256 * sizeof(float), stream);
    scatter_k<<<scatter_blocks, blk, 0, stream>>>(out, ei, s, nullptr, 0);
    gemm_agg_k<<<gemm_blocks, blk, 0, stream>>>(out, s, cnt, W1_1, b1_1, h1, colsum, colsq);
    bnstats_k<<<1, 128, 0, stream>>>(colsum, colsq, g_1, be_1, scale, shift);
    gemm_bn_k<<<gemm_blocks, blk, 0, stream>>>(h1, scale, shift, W2_1, b2_1, out, 0);
}

// Round 2
// 1079.227 us; speedup vs baseline: 5.4532x; 5.4532x over previous
//
#include <hip/hip_runtime.h>

#define N_NODES 100000
#define N_EDGES 1600000
#define DIM 128

// ===========================================================================
// CSR build (once per call; dst identical for both layers)
// ===========================================================================
__global__ __launch_bounds__(256) void deg_k(const int* __restrict__ ei, int* __restrict__ deg)
{
    int e = blockIdx.x * 256 + threadIdx.x;
    if (e < N_EDGES) atomicAdd(deg + ei[N_EDGES + e], 1);
}

// single-block exclusive scan over deg -> rowptr, and init cursor = rowptr
__global__ __launch_bounds__(1024) void scan_k(const int* __restrict__ deg,
                                               int* __restrict__ rowptr,
                                               int* __restrict__ cursor)
{
    __shared__ int part[1024];
    const int T = 1024;
    int t = threadIdx.x;
    const int chunk = (N_NODES + T - 1) / T;          // 98
    int lo = t * chunk;
    int hi = lo + chunk; if (hi > N_NODES) hi = N_NODES;
    int s = 0;
    for (int i = lo; i < hi; ++i) s += deg[i];
    part[t] = s;
    __syncthreads();
    // Hillis-Steele inclusive scan
    for (int off = 1; off < T; off <<= 1) {
        int add = (t >= off) ? part[t - off] : 0;
        __syncthreads();
        part[t] += add;
        __syncthreads();
    }
    int run = part[t] - s;                            // exclusive prefix
    for (int i = lo; i < hi; ++i) {
        rowptr[i] = run;
        cursor[i] = run;
        run += deg[i];
    }
    if (t == T - 1) rowptr[N_NODES] = run;
}

__global__ __launch_bounds__(256) void fill_k(const int* __restrict__ ei,
                                              int* __restrict__ cursor,
                                              int* __restrict__ csr_src)
{
    int e = blockIdx.x * 256 + threadIdx.x;
    if (e >= N_EDGES) return;
    int src = ei[e];
    int dst = ei[N_EDGES + e];
    int pos = atomicAdd(cursor + dst, 1);
    csr_src[pos] = src;
}

// ===========================================================================
// Gather aggregation: one wave per node; lane l covers channels {2l, 2l+1}.
// a[n] = x[n] + (1/max(deg,1)) * sum_{e in CSR[n]} x[src_e]
// ===========================================================================
__global__ __launch_bounds__(256) void agg_k(const float* __restrict__ x,
                                             const int* __restrict__ rowptr,
                                             const int* __restrict__ csr_src,
                                             float* __restrict__ a)
{
    int wid = (blockIdx.x * 256 + threadIdx.x) >> 6;  // node id
    if (wid >= N_NODES) return;
    int lane = threadIdx.x & 63;
    int beg = rowptr[wid], end = rowptr[wid + 1];
    float ax = 0.f, ay = 0.f;
    int e = beg;
    for (; e + 4 <= end; e += 4) {                    // 4-way MLP
        int s0 = csr_src[e], s1 = csr_src[e + 1], s2 = csr_src[e + 2], s3 = csr_src[e + 3];
        float2 v0 = *(const float2*)(x + s0 * DIM + lane * 2);
        float2 v1 = *(const float2*)(x + s1 * DIM + lane * 2);
        float2 v2 = *(const float2*)(x + s2 * DIM + lane * 2);
        float2 v3 = *(const float2*)(x + s3 * DIM + lane * 2);
        ax += (v0.x + v1.x) + (v2.x + v3.x);
        ay += (v0.y + v1.y) + (v2.y + v3.y);
    }
    for (; e < end; ++e) {
        int s0 = csr_src[e];
        float2 v0 = *(const float2*)(x + s0 * DIM + lane * 2);
        ax += v0.x; ay += v0.y;
    }
    float inv = 1.0f / fmaxf((float)(end - beg), 1.0f);
    float2 xv = *(const float2*)(x + wid * DIM + lane * 2);
    float2 o;
    o.x = xv.x + ax * inv;
    o.y = xv.y + ay * inv;
    *(float2*)(a + wid * DIM + lane * 2) = o;
}

// ===========================================================================
// GEMM1 + fused BN stats. Reads pre-combined A rows from `ah`, writes h1
// IN-PLACE into `ah` (each block reads only its own 64 rows before writing).
// ===========================================================================
__global__ __launch_bounds__(256) void gemm_agg_k(
    float* ah,
    const float* __restrict__ W, const float* __restrict__ bias,
    float* __restrict__ colsum, float* __restrict__ colsq)
{
    __shared__ float lds[64 * 132];
    const int t = threadIdx.x;
    const int row0 = blockIdx.x * 64;

    for (int i = t; i < 64 * 32; i += 256) {
        int r = i >> 5;
        int c = (i & 31) << 2;
        int gr = row0 + r;
        float4 v = make_float4(0.f, 0.f, 0.f, 0.f);
        if (gr < N_NODES) v = *(const float4*)(ah + gr * DIM + c);
        *(float4*)(lds + r * 132 + c) = v;
    }
    __syncthreads();

    const int tx = t & 15, ty = t >> 4;
    const int j0 = tx * 8;
    float acc[4][8];
    #pragma unroll
    for (int r = 0; r < 4; ++r)
        #pragma unroll
        for (int c = 0; c < 8; ++c) acc[r][c] = 0.f;

    #pragma unroll 4
    for (int k = 0; k < DIM; ++k) {
        float4 w0 = *(const float4*)(W + k * DIM + j0);
        float4 w1 = *(const float4*)(W + k * DIM + j0 + 4);
        float wv[8] = {w0.x, w0.y, w0.z, w0.w, w1.x, w1.y, w1.z, w1.w};
        #pragma unroll
        for (int r = 0; r < 4; ++r) {
            float a = lds[(ty * 4 + r) * 132 + k];
            #pragma unroll
            for (int c = 0; c < 8; ++c) acc[r][c] = fmaf(a, wv[c], acc[r][c]);
        }
    }

    float4 bv0 = *(const float4*)(bias + j0);
    float4 bv1 = *(const float4*)(bias + j0 + 4);
    float bb[8] = {bv0.x, bv0.y, bv0.z, bv0.w, bv1.x, bv1.y, bv1.z, bv1.w};
    float psum[8], psq[8];
    #pragma unroll
    for (int c = 0; c < 8; ++c) { psum[c] = 0.f; psq[c] = 0.f; }
    #pragma unroll
    for (int r = 0; r < 4; ++r) {
        int gr = row0 + ty * 4 + r;
        if (gr < N_NODES) {
            float vals[8];
            #pragma unroll
            for (int c = 0; c < 8; ++c) {
                float v = acc[r][c] + bb[c];
                vals[c] = v;
                psum[c] += v;
                psq[c] += v * v;
            }
            *(float4*)(ah + gr * DIM + j0)     = make_float4(vals[0], vals[1], vals[2], vals[3]);
            *(float4*)(ah + gr * DIM + j0 + 4) = make_float4(vals[4], vals[5], vals[6], vals[7]);
        }
    }

    __syncthreads();
    #pragma unroll
    for (int c = 0; c < 8; ++c) {
        lds[ty * 128 + j0 + c]        = psum[c];
        lds[2048 + ty * 128 + j0 + c] = psq[c];
    }
    __syncthreads();
    if (t < 128) {
        float ss = 0.f, sq = 0.f;
        #pragma unroll
        for (int u = 0; u < 16; ++u) {
            ss += lds[u * 128 + t];
            sq += lds[2048 + u * 128 + t];
        }
        atomicAdd(colsum + t, ss);
        atomicAdd(colsq + t, sq);
    }
}

__global__ void bnstats_k(const float* __restrict__ colsum, const float* __restrict__ colsq,
                          const float* __restrict__ gamma, const float* __restrict__ beta,
                          float* __restrict__ scale, float* __restrict__ shift)
{
    int j = threadIdx.x;
    const float inv_n = 1.0f / (float)N_NODES;
    float mu = colsum[j] * inv_n;
    float var = colsq[j] * inv_n - mu * mu;   // biased variance (torch BN)
    float sc = gamma[j] * rsqrtf(var + 1e-5f);
    scale[j] = sc;
    shift[j] = beta[j] - mu * sc;
}

// ===========================================================================
// GEMM2: out = relu_opt( relu(h1*scale+shift) @ W2 + b2 )
// ===========================================================================
__global__ __launch_bounds__(256) void gemm_bn_k(
    const float* __restrict__ h1, const float* __restrict__ scale, const float* __restrict__ shift,
    const float* __restrict__ W, const float* __restrict__ bias,
    float* __restrict__ out, int relu_out)
{
    __shared__ float lds[64 * 132];
    const int t = threadIdx.x;
    const int row0 = blockIdx.x * 64;

    for (int i = t; i < 64 * 32; i += 256) {
        int r = i >> 5;
        int c = (i & 31) << 2;
        int gr = row0 + r;
        float4 v = make_float4(0.f, 0.f, 0.f, 0.f);
        if (gr < N_NODES) {
            float4 hv = *(const float4*)(h1 + gr * DIM + c);
            float4 sc = *(const float4*)(scale + c);
            float4 sh = *(const float4*)(shift + c);
            v.x = fmaxf(hv.x * sc.x + sh.x, 0.f);
            v.y = fmaxf(hv.y * sc.y + sh.y, 0.f);
            v.z = fmaxf(hv.z * sc.z + sh.z, 0.f);
            v.w = fmaxf(hv.w * sc.w + sh.w, 0.f);
        }
        *(float4*)(lds + r * 132 + c) = v;
    }
    __syncthreads();

    const int tx = t & 15, ty = t >> 4;
    const int j0 = tx * 8;
    float acc[4][8];
    #pragma unroll
    for (int r = 0; r < 4; ++r)
        #pragma unroll
        for (int c = 0; c < 8; ++c) acc[r][c] = 0.f;

    #pragma unroll 4
    for (int k = 0; k < DIM; ++k) {
        float4 w0 = *(const float4*)(W + k * DIM + j0);
        float4 w1 = *(const float4*)(W + k * DIM + j0 + 4);
        float wv[8] = {w0.x, w0.y, w0.z, w0.w, w1.x, w1.y, w1.z, w1.w};
        #pragma unroll
        for (int r = 0; r < 4; ++r) {
            float a = lds[(ty * 4 + r) * 132 + k];
            #pragma unroll
            for (int c = 0; c < 8; ++c) acc[r][c] = fmaf(a, wv[c], acc[r][c]);
        }
    }

    float4 bv0 = *(const float4*)(bias + j0);
    float4 bv1 = *(const float4*)(bias + j0 + 4);
    float bb[8] = {bv0.x, bv0.y, bv0.z, bv0.w, bv1.x, bv1.y, bv1.z, bv1.w};
    #pragma unroll
    for (int r = 0; r < 4; ++r) {
        int gr = row0 + ty * 4 + r;
        if (gr < N_NODES) {
            float vals[8];
            #pragma unroll
            for (int c = 0; c < 8; ++c) {
                float v = acc[r][c] + bb[c];
                if (relu_out) v = fmaxf(v, 0.f);
                vals[c] = v;
            }
            *(float4*)(out + gr * DIM + j0)     = make_float4(vals[0], vals[1], vals[2], vals[3]);
            *(float4*)(out + gr * DIM + j0 + 4) = make_float4(vals[4], vals[5], vals[6], vals[7]);
        }
    }
}

// ---------------------------------------------------------------------------
// Workspace layout:
//   floats: ah (a/h1 aliased, 12.8M) @ 0; colsum@12.8M, colsq@+128,
//           scale@+256, shift@+384
//   ints (after 12,800,512 floats): deg[100k], rowptr[100,001],
//           cursor[100k], csr_src[1.6M]
// Total ≈ 58.8 MB.
// ---------------------------------------------------------------------------
extern "C" void kernel_launch(void* const* d_in, const int* in_sizes, int n_in,
                              void* d_out, int out_size, void* d_ws, size_t ws_size,
                              hipStream_t stream)
{
    const float* x    = (const float*)d_in[0];
    const int*   ei   = (const int*)d_in[1];
    const float* W1_0 = (const float*)d_in[2];
    const float* b1_0 = (const float*)d_in[3];
    const float* g_0  = (const float*)d_in[4];
    const float* be_0 = (const float*)d_in[5];
    const float* W2_0 = (const float*)d_in[6];
    const float* b2_0 = (const float*)d_in[7];
    const float* W1_1 = (const float*)d_in[8];
    const float* b1_1 = (const float*)d_in[9];
    const float* g_1  = (const float*)d_in[10];
    const float* be_1 = (const float*)d_in[11];
    const float* W2_1 = (const float*)d_in[12];
    const float* b2_1 = (const float*)d_in[13];
    float* out = (float*)d_out;
    float* ws  = (float*)d_ws;

    float* ah     = ws;
    float* colsum = ws + 12800000;
    float* colsq  = colsum + 128;
    float* scale  = colsum + 256;
    float* shift  = colsum + 384;
    int* ibase   = (int*)(ws + 12800512);
    int* deg     = ibase;
    int* rowptr  = ibase + 100000;
    int* cursor  = ibase + 200001;
    int* csr_src = ibase + 300001;

    dim3 blk(256);
    int edge_blocks = (N_EDGES + 255) / 256;           // 6250
    int gemm_blocks = (N_NODES + 63) / 64;             // 1563
    int agg_blocks  = (N_NODES * 64 + 255) / 256;      // 25000

    // ---- CSR build (shared by both layers) ----
    hipMemsetAsync(deg, 0, N_NODES * sizeof(int), stream);
    deg_k<<<edge_blocks, blk, 0, stream>>>(ei, deg);
    scan_k<<<1, 1024, 0, stream>>>(deg, rowptr, cursor);
    fill_k<<<edge_blocks, blk, 0, stream>>>(ei, cursor, csr_src);

    // ---- layer 0 ----
    hipMemsetAsync(colsum, 0, 256 * sizeof(float), stream);
    agg_k<<<agg_blocks, blk, 0, stream>>>(x, rowptr, csr_src, ah);
    gemm_agg_k<<<gemm_blocks, blk, 0, stream>>>(ah, W1_0, b1_0, colsum, colsq);
    bnstats_k<<<1, 128, 0, stream>>>(colsum, colsq, g_0, be_0, scale, shift);
    gemm_bn_k<<<gemm_blocks, blk, 0, stream>>>(ah, scale, shift, W2_0, b2_0, out, 1);

    // ---- layer 1 ----
    hipMemsetAsync(colsum, 0, 256 * sizeof(float), stream);
    agg_k<<<agg_blocks, blk, 0, stream>>>(out, rowptr, csr_src, ah);
    gemm_agg_k<<<gemm_blocks, blk, 0, stream>>>(ah, W1_1, b1_1, colsum, colsq);
    bnstats_k<<<1, 128, 0, stream>>>(colsum, colsq, g_1, be_1, scale, shift);
    gemm_bn_k<<<gemm_blocks, blk, 0, stream>>>(ah, scale, shift, W2_1, b2_1, out, 0);
}

// Round 3
// 853.891 us; speedup vs baseline: 6.8922x; 1.2639x over previous
//
#include <hip/hip_runtime.h>

#define N_NODES 100000
#define N_EDGES 1600000
#define DIM 128

#define SCAN_CHUNK 256
#define SCAN_BLOCKS ((N_NODES + SCAN_CHUNK - 1) / SCAN_CHUNK)   // 391

// ===========================================================================
// CSR build (once per call; dst identical for both layers)
// ===========================================================================
__global__ __launch_bounds__(256) void deg_k(const int* __restrict__ ei, int* __restrict__ deg)
{
    int e = blockIdx.x * 256 + threadIdx.x;
    if (e < N_EDGES) atomicAdd(deg + ei[N_EDGES + e], 1);
}

// --- parallel scan, stage 1: per-block reduction of deg chunks ---
__global__ __launch_bounds__(256) void scan_reduce_k(const int* __restrict__ deg,
                                                     int* __restrict__ blocksum)
{
    __shared__ int red[256];
    int t = threadIdx.x;
    int i = blockIdx.x * SCAN_CHUNK + t;
    int v = (i < N_NODES) ? deg[i] : 0;
    red[t] = v;
    __syncthreads();
    #pragma unroll
    for (int off = 128; off > 0; off >>= 1) {
        if (t < off) red[t] += red[t + off];
        __syncthreads();
    }
    if (t == 0) blocksum[blockIdx.x] = red[0];
}

// --- stage 2: single small block scans the 391 blocksums (exclusive) ---
__global__ __launch_bounds__(512) void scan_blocks_k(const int* __restrict__ blocksum,
                                                     int* __restrict__ blockoff)
{
    __shared__ int part[512];
    int t = threadIdx.x;
    int v = (t < SCAN_BLOCKS) ? blocksum[t] : 0;
    part[t] = v;
    __syncthreads();
    #pragma unroll
    for (int off = 1; off < 512; off <<= 1) {
        int add = (t >= off) ? part[t - off] : 0;
        __syncthreads();
        part[t] += add;
        __syncthreads();
    }
    if (t < SCAN_BLOCKS) blockoff[t] = part[t] - v;   // exclusive
}

// --- stage 3: block-local exclusive scan + block offset -> rowptr/cursor ---
__global__ __launch_bounds__(256) void scan_final_k(const int* __restrict__ deg,
                                                    const int* __restrict__ blockoff,
                                                    int* __restrict__ rowptr,
                                                    int* __restrict__ cursor)
{
    __shared__ int part[256];
    int t = threadIdx.x;
    int i = blockIdx.x * SCAN_CHUNK + t;
    int v = (i < N_NODES) ? deg[i] : 0;
    part[t] = v;
    __syncthreads();
    #pragma unroll
    for (int off = 1; off < 256; off <<= 1) {
        int add = (t >= off) ? part[t - off] : 0;
        __syncthreads();
        part[t] += add;
        __syncthreads();
    }
    int excl = blockoff[blockIdx.x] + part[t] - v;
    if (i < N_NODES) {
        rowptr[i] = excl;
        cursor[i] = excl;
        if (i == N_NODES - 1) rowptr[N_NODES] = excl + v;
    }
}

__global__ __launch_bounds__(256) void fill_k(const int* __restrict__ ei,
                                              int* __restrict__ cursor,
                                              int* __restrict__ csr_src)
{
    int e = blockIdx.x * 256 + threadIdx.x;
    if (e >= N_EDGES) return;
    int src = ei[e];
    int dst = ei[N_EDGES + e];
    int pos = atomicAdd(cursor + dst, 1);
    csr_src[pos] = src;
}

// ===========================================================================
// Gather aggregation: one wave per node; lane l covers channels {2l, 2l+1}.
// a[n] = x[n] + (1/max(deg,1)) * sum_{e in CSR[n]} x[src_e]
// ===========================================================================
__global__ __launch_bounds__(256) void agg_k(const float* __restrict__ x,
                                             const int* __restrict__ rowptr,
                                             const int* __restrict__ csr_src,
                                             float* __restrict__ a)
{
    int wid = (blockIdx.x * 256 + threadIdx.x) >> 6;  // node id
    if (wid >= N_NODES) return;
    int lane = threadIdx.x & 63;
    int beg = rowptr[wid], end = rowptr[wid + 1];
    float ax = 0.f, ay = 0.f;
    int e = beg;
    for (; e + 4 <= end; e += 4) {                    // 4-way MLP
        int s0 = csr_src[e], s1 = csr_src[e + 1], s2 = csr_src[e + 2], s3 = csr_src[e + 3];
        float2 v0 = *(const float2*)(x + s0 * DIM + lane * 2);
        float2 v1 = *(const float2*)(x + s1 * DIM + lane * 2);
        float2 v2 = *(const float2*)(x + s2 * DIM + lane * 2);
        float2 v3 = *(const float2*)(x + s3 * DIM + lane * 2);
        ax += (v0.x + v1.x) + (v2.x + v3.x);
        ay += (v0.y + v1.y) + (v2.y + v3.y);
    }
    for (; e < end; ++e) {
        int s0 = csr_src[e];
        float2 v0 = *(const float2*)(x + s0 * DIM + lane * 2);
        ax += v0.x; ay += v0.y;
    }
    float inv = 1.0f / fmaxf((float)(end - beg), 1.0f);
    float2 xv = *(const float2*)(x + wid * DIM + lane * 2);
    float2 o;
    o.x = xv.x + ax * inv;
    o.y = xv.y + ay * inv;
    *(float2*)(a + wid * DIM + lane * 2) = o;
}

// ===========================================================================
// GEMM1 + fused BN stats. Reads pre-combined A rows from `ah`, writes h1
// IN-PLACE into `ah` (each block reads only its own 64 rows before writing).
// ===========================================================================
__global__ __launch_bounds__(256) void gemm_agg_k(
    float* ah,
    const float* __restrict__ W, const float* __restrict__ bias,
    float* __restrict__ colsum, float* __restrict__ colsq)
{
    __shared__ float lds[64 * 132];
    const int t = threadIdx.x;
    const int row0 = blockIdx.x * 64;

    for (int i = t; i < 64 * 32; i += 256) {
        int r = i >> 5;
        int c = (i & 31) << 2;
        int gr = row0 + r;
        float4 v = make_float4(0.f, 0.f, 0.f, 0.f);
        if (gr < N_NODES) v = *(const float4*)(ah + gr * DIM + c);
        *(float4*)(lds + r * 132 + c) = v;
    }
    __syncthreads();

    const int tx = t & 15, ty = t >> 4;
    const int j0 = tx * 8;
    float acc[4][8];
    #pragma unroll
    for (int r = 0; r < 4; ++r)
        #pragma unroll
        for (int c = 0; c < 8; ++c) acc[r][c] = 0.f;

    #pragma unroll 4
    for (int k = 0; k < DIM; ++k) {
        float4 w0 = *(const float4*)(W + k * DIM + j0);
        float4 w1 = *(const float4*)(W + k * DIM + j0 + 4);
        float wv[8] = {w0.x, w0.y, w0.z, w0.w, w1.x, w1.y, w1.z, w1.w};
        #pragma unroll
        for (int r = 0; r < 4; ++r) {
            float a = lds[(ty * 4 + r) * 132 + k];
            #pragma unroll
            for (int c = 0; c < 8; ++c) acc[r][c] = fmaf(a, wv[c], acc[r][c]);
        }
    }

    float4 bv0 = *(const float4*)(bias + j0);
    float4 bv1 = *(const float4*)(bias + j0 + 4);
    float bb[8] = {bv0.x, bv0.y, bv0.z, bv0.w, bv1.x, bv1.y, bv1.z, bv1.w};
    float psum[8], psq[8];
    #pragma unroll
    for (int c = 0; c < 8; ++c) { psum[c] = 0.f; psq[c] = 0.f; }
    #pragma unroll
    for (int r = 0; r < 4; ++r) {
        int gr = row0 + ty * 4 + r;
        if (gr < N_NODES) {
            float vals[8];
            #pragma unroll
            for (int c = 0; c < 8; ++c) {
                float v = acc[r][c] + bb[c];
                vals[c] = v;
                psum[c] += v;
                psq[c] += v * v;
            }
            *(float4*)(ah + gr * DIM + j0)     = make_float4(vals[0], vals[1], vals[2], vals[3]);
            *(float4*)(ah + gr * DIM + j0 + 4) = make_float4(vals[4], vals[5], vals[6], vals[7]);
        }
    }

    __syncthreads();
    #pragma unroll
    for (int c = 0; c < 8; ++c) {
        lds[ty * 128 + j0 + c]        = psum[c];
        lds[2048 + ty * 128 + j0 + c] = psq[c];
    }
    __syncthreads();
    if (t < 128) {
        float ss = 0.f, sq = 0.f;
        #pragma unroll
        for (int u = 0; u < 16; ++u) {
            ss += lds[u * 128 + t];
            sq += lds[2048 + u * 128 + t];
        }
        atomicAdd(colsum + t, ss);
        atomicAdd(colsq + t, sq);
    }
}

__global__ void bnstats_k(const float* __restrict__ colsum, const float* __restrict__ colsq,
                          const float* __restrict__ gamma, const float* __restrict__ beta,
                          float* __restrict__ scale, float* __restrict__ shift)
{
    int j = threadIdx.x;
    const float inv_n = 1.0f / (float)N_NODES;
    float mu = colsum[j] * inv_n;
    float var = colsq[j] * inv_n - mu * mu;   // biased variance (torch BN)
    float sc = gamma[j] * rsqrtf(var + 1e-5f);
    scale[j] = sc;
    shift[j] = beta[j] - mu * sc;
}

// ===========================================================================
// GEMM2: out = relu_opt( relu(h1*scale+shift) @ W2 + b2 )
// ===========================================================================
__global__ __launch_bounds__(256) void gemm_bn_k(
    const float* __restrict__ h1, const float* __restrict__ scale, const float* __restrict__ shift,
    const float* __restrict__ W, const float* __restrict__ bias,
    float* __restrict__ out, int relu_out)
{
    __shared__ float lds[64 * 132];
    const int t = threadIdx.x;
    const int row0 = blockIdx.x * 64;

    for (int i = t; i < 64 * 32; i += 256) {
        int r = i >> 5;
        int c = (i & 31) << 2;
        int gr = row0 + r;
        float4 v = make_float4(0.f, 0.f, 0.f, 0.f);
        if (gr < N_NODES) {
            float4 hv = *(const float4*)(h1 + gr * DIM + c);
            float4 sc = *(const float4*)(scale + c);
            float4 sh = *(const float4*)(shift + c);
            v.x = fmaxf(hv.x * sc.x + sh.x, 0.f);
            v.y = fmaxf(hv.y * sc.y + sh.y, 0.f);
            v.z = fmaxf(hv.z * sc.z + sh.z, 0.f);
            v.w = fmaxf(hv.w * sc.w + sh.w, 0.f);
        }
        *(float4*)(lds + r * 132 + c) = v;
    }
    __syncthreads();

    const int tx = t & 15, ty = t >> 4;
    const int j0 = tx * 8;
    float acc[4][8];
    #pragma unroll
    for (int r = 0; r < 4; ++r)
        #pragma unroll
        for (int c = 0; c < 8; ++c) acc[r][c] = 0.f;

    #pragma unroll 4
    for (int k = 0; k < DIM; ++k) {
        float4 w0 = *(const float4*)(W + k * DIM + j0);
        float4 w1 = *(const float4*)(W + k * DIM + j0 + 4);
        float wv[8] = {w0.x, w0.y, w0.z, w0.w, w1.x, w1.y, w1.z, w1.w};
        #pragma unroll
        for (int r = 0; r < 4; ++r) {
            float a = lds[(ty * 4 + r) * 132 + k];
            #pragma unroll
            for (int c = 0; c < 8; ++c) acc[r][c] = fmaf(a, wv[c], acc[r][c]);
        }
    }

    float4 bv0 = *(const float4*)(bias + j0);
    float4 bv1 = *(const float4*)(bias + j0 + 4);
    float bb[8] = {bv0.x, bv0.y, bv0.z, bv0.w, bv1.x, bv1.y, bv1.z, bv1.w};
    #pragma unroll
    for (int r = 0; r < 4; ++r) {
        int gr = row0 + ty * 4 + r;
        if (gr < N_NODES) {
            float vals[8];
            #pragma unroll
            for (int c = 0; c < 8; ++c) {
                float v = acc[r][c] + bb[c];
                if (relu_out) v = fmaxf(v, 0.f);
                vals[c] = v;
            }
            *(float4*)(out + gr * DIM + j0)     = make_float4(vals[0], vals[1], vals[2], vals[3]);
            *(float4*)(out + gr * DIM + j0 + 4) = make_float4(vals[4], vals[5], vals[6], vals[7]);
        }
    }
}

// ---------------------------------------------------------------------------
// Workspace layout:
//   floats: ah (a/h1 aliased, 12.8M) @ 0; colsum@12.8M, colsq@+128,
//           scale@+256, shift@+384
//   ints (after 12,800,512 floats): deg[100k], rowptr[100,001],
//           cursor[100k], csr_src[1.6M], blocksum[391], blockoff[391]
// ---------------------------------------------------------------------------
extern "C" void kernel_launch(void* const* d_in, const int* in_sizes, int n_in,
                              void* d_out, int out_size, void* d_ws, size_t ws_size,
                              hipStream_t stream)
{
    const float* x    = (const float*)d_in[0];
    const int*   ei   = (const int*)d_in[1];
    const float* W1_0 = (const float*)d_in[2];
    const float* b1_0 = (const float*)d_in[3];
    const float* g_0  = (const float*)d_in[4];
    const float* be_0 = (const float*)d_in[5];
    const float* W2_0 = (const float*)d_in[6];
    const float* b2_0 = (const float*)d_in[7];
    const float* W1_1 = (const float*)d_in[8];
    const float* b1_1 = (const float*)d_in[9];
    const float* g_1  = (const float*)d_in[10];
    const float* be_1 = (const float*)d_in[11];
    const float* W2_1 = (const float*)d_in[12];
    const float* b2_1 = (const float*)d_in[13];
    float* out = (float*)d_out;
    float* ws  = (float*)d_ws;

    float* ah     = ws;
    float* colsum = ws + 12800000;
    float* colsq  = colsum + 128;
    float* scale  = colsum + 256;
    float* shift  = colsum + 384;
    int* ibase    = (int*)(ws + 12800512);
    int* deg      = ibase;
    int* rowptr   = ibase + 100000;
    int* cursor   = ibase + 200001;
    int* csr_src  = ibase + 300001;
    int* blocksum = ibase + 1900001;
    int* blockoff = ibase + 1900501;

    dim3 blk(256);
    int edge_blocks = (N_EDGES + 255) / 256;           // 6250
    int gemm_blocks = (N_NODES + 63) / 64;             // 1563
    int agg_blocks  = (N_NODES * 64 + 255) / 256;      // 25000

    // ---- CSR build (shared by both layers) ----
    hipMemsetAsync(deg, 0, N_NODES * sizeof(int), stream);
    deg_k<<<edge_blocks, blk, 0, stream>>>(ei, deg);
    scan_reduce_k<<<SCAN_BLOCKS, blk, 0, stream>>>(deg, blocksum);
    scan_blocks_k<<<1, 512, 0, stream>>>(blocksum, blockoff);
    scan_final_k<<<SCAN_BLOCKS, blk, 0, stream>>>(deg, blockoff, rowptr, cursor);
    fill_k<<<edge_blocks, blk, 0, stream>>>(ei, cursor, csr_src);

    // ---- layer 0 ----
    hipMemsetAsync(colsum, 0, 256 * sizeof(float), stream);
    agg_k<<<agg_blocks, blk, 0, stream>>>(x, rowptr, csr_src, ah);
    gemm_agg_k<<<gemm_blocks, blk, 0, stream>>>(ah, W1_0, b1_0, colsum, colsq);
    bnstats_k<<<1, 128, 0, stream>>>(colsum, colsq, g_0, be_0, scale, shift);
    gemm_bn_k<<<gemm_blocks, blk, 0, stream>>>(ah, scale, shift, W2_0, b2_0, out, 1);

    // ---- layer 1 ----
    hipMemsetAsync(colsum, 0, 256 * sizeof(float), stream);
    agg_k<<<agg_blocks, blk, 0, stream>>>(out, rowptr, csr_src, ah);
    gemm_agg_k<<<gemm_blocks, blk, 0, stream>>>(ah, W1_1, b1_1, colsum, colsq);
    bnstats_k<<<1, 128, 0, stream>>>(colsum, colsq, g_1, be_1, scale, shift);
    gemm_bn_k<<<gemm_blocks, blk, 0, stream>>>(ah, scale, shift, W2_1, b2_1, out, 0);
}